// Round 6
// baseline (107.303 us; speedup 1.0000x reference)
//
#include <hip/hip_runtime.h>
#include <hip/hip_bf16.h>
#include <math.h>
#include <string.h>

constexpr int VOCAB  = 32000;
constexpr int D      = 128;
constexpr int T      = 32;
constexpr int NCELLS = 8 * 100 * 64;   // 51200
constexpr int NCHUNK = 2;              // D split into 2 chunks of 64 dims
constexpr int CDIM   = D / NCHUNK;     // 64 dims (128 B bf16 per row slice)
constexpr int CHUNK_ELEMS2 = VOCAB * (CDIM / 2);  // bf162 elems per chunk slice

// ---- helpers
__device__ inline ushort f2bf(float f) {
    uint32_t u;
    memcpy(&u, &f, 4);
    u += 0x7FFFu + ((u >> 16) & 1u);   // RTN-even
    return (ushort)(u >> 16);
}

// Fast exact-erf GELU: Abramowitz-Stegun 7.1.26 (|erf err| <= 1.5e-7).
__device__ inline float gelu_fast(float xv) {
    const float is2 = 0.70710678118654752440f;
    float y  = xv * is2;
    float av = fabsf(y);
    float t  = __builtin_amdgcn_rcpf(__builtin_fmaf(0.3275911f, av, 1.0f));
    float p  = 0.254829592f + t * (-0.284496736f + t * (1.421413741f
             + t * (-1.453152027f + t * 1.061405429f)));
    float e  = __expf(-av * av);
    float er = 1.0f - p * t * e;
    er = copysignf(er, y);
    return 0.5f * xv * (1.0f + er);
}

// Kernel 1: convert W_embed f32 -> bf16 chunked [chunk][vocab][CDIM]; also
// zero-init out.
__global__ __launch_bounds__(256) void convert_W_kernel(
    const float* __restrict__ W, ushort* __restrict__ Wb, float* __restrict__ out)
{
    const int i = blockIdx.x * blockDim.x + threadIdx.x;  // ushort4 group id
    const int v = i >> 5;        // vocab row (32 groups of 4 dims per row)
    const int k = i & 31;
    const int chunk = k >> 4;    // 16 groups (64 dims) per chunk
    const int sub   = k & 15;

    float4 src = reinterpret_cast<const float4*>(W)[i];
    ushort4 o;
    o.x = f2bf(src.x); o.y = f2bf(src.y); o.z = f2bf(src.z); o.w = f2bf(src.w);
    reinterpret_cast<ushort4*>(Wb)[(size_t)chunk * (VOCAB * 16) + (size_t)v * 16 + sub] = o;

    if (i < NCELLS) out[i] = 0.0f;
}

// Kernel 2: one wave per (cell, chunk); blockIdx%8 steers chunk to XCD halves
// so each XCD's L2 caches one 4.1 MB slice.
// Token indices are read through the SCALAR path (cell forced uniform via
// readfirstlane -> s_load_dwordx16), so the 16 gather loads are fully
// independent and software-pipelined (no ds_bpermute / vmcnt(0) serialization).
__global__ __launch_bounds__(256) void gather_kernel(
    const int*    __restrict__ x,       // [NCELLS, T]
    const ushort* __restrict__ Wb,      // [NCHUNK][VOCAB][CDIM] bf16 bits
    const float*  __restrict__ w_pred,  // [1, D]
    const float*  __restrict__ b_pred,  // [1]
    float*        __restrict__ out)     // [NCELLS] (zeroed by convert kernel)
{
    const int wave = threadIdx.x >> 6;
    const int lane = threadIdx.x & 63;

    const int slot  = blockIdx.x & 7;
    const int chunk = slot >> 2;               // 4 XCDs per chunk
    const int sub   = slot & 3;
    const int g     = blockIdx.x >> 3;         // 0..3199
    // wave-uniform cell, forced into an SGPR so x-loads go scalar
    const int cell  = __builtin_amdgcn_readfirstlane(((g << 2) + sub) * 4 + wave);

    const int j    = lane & 31;   // bf162 index: dims 2j, 2j+1 of chunk
    const bool hi  = lane >= 32;  // half-wave: even vs odd tokens

    const int* __restrict__ xp = x + (size_t)cell * T;   // uniform -> s_load

    // Phase 1: all 16 offsets (bf162 element units), no memory dependencies.
    uint32_t off[T / 2];
    #pragma unroll
    for (int i = 0; i < T / 2; ++i) {
        int row = hi ? xp[2 * i + 1] : xp[2 * i];        // cndmask of 2 SGPRs
        off[i] = ((uint32_t)row << 5) + (uint32_t)j;
    }

    const __hip_bfloat162* __restrict__ tbl =
        reinterpret_cast<const __hip_bfloat162*>(Wb) + (size_t)chunk * CHUNK_ELEMS2;

    // Phase 2: 16 independent gather loads, pipelined accumulate.
    float ax = 0.0f, ay = 0.0f;
    float bx = 0.0f, by = 0.0f;
    #pragma unroll
    for (int i = 0; i < T / 2; i += 2) {
        __hip_bfloat162 v0 = tbl[off[i]];
        __hip_bfloat162 v1 = tbl[off[i + 1]];
        float2 f0 = __bfloat1622float2(v0);
        float2 f1 = __bfloat1622float2(v1);
        ax += f0.x; ay += f0.y;
        bx += f1.x; by += f1.y;
    }
    ax += bx; ay += by;

    // combine the two half-wave token subsets (even vs odd tokens)
    ax += __shfl_xor(ax, 32, 64);
    ay += __shfl_xor(ay, 32, 64);

    // lane owns chunk-dim d = 2j + (hi?1:0)
    float p  = (hi ? ay : ax) * (1.0f / (float)T);
    float gl = gelu_fast(p);
    float wv = w_pred[chunk * CDIM + 2 * j + (hi ? 1 : 0)];
    float s  = gl * wv;

    #pragma unroll
    for (int offm = 32; offm >= 1; offm >>= 1)
        s += __shfl_xor(s, offm, 64);

    if (lane == 0) {
        if (chunk == 0) s += b_pred[0];
        atomicAdd(&out[cell], s);
    }
}

extern "C" void kernel_launch(void* const* d_in, const int* in_sizes, int n_in,
                              void* d_out, int out_size, void* d_ws, size_t ws_size,
                              hipStream_t stream) {
    const int*   x      = (const int*)  d_in[0];
    const float* W      = (const float*)d_in[1];
    const float* w_pred = (const float*)d_in[2];
    const float* b_pred = (const float*)d_in[3];
    float*       out    = (float*)d_out;
    ushort*      Wb     = (ushort*)d_ws;   // VOCAB*D*2 = 8.192 MB

    const int conv_groups = VOCAB * D / 4;                 // 1,024,000
    convert_W_kernel<<<conv_groups / 256, 256, 0, stream>>>(W, Wb, out);

    // 2 chunks x 12800 cell-blocks (4 cells per block) = 25600 blocks
    gather_kernel<<<NCHUNK * (NCELLS / 4), 256, 0, stream>>>(x, Wb, w_pred, b_pred, out);
}